// Round 13
// baseline (191.334 us; speedup 1.0000x reference)
//
#include <hip/hip_runtime.h>
#include <hip/hip_bf16.h>
#include <math.h>

// ---------------- workspace layout (float indices) ----------------
// [0,192)     : refsum partials  [bc=48][chunk=4]
// [192,256)   : gates[b*4+e]
// [256,24832) : gate-dot partials [c=3][chunk=64][b=16][8]  (G[4] then N[4])
// [25088,29184): packed conv1 A-frags  (1024 uint4)
// [29184,31232): packed conv2 B-frags  (512 uint4)
// [31232,31616): completion flags (384 ints; poison 0xAA != 1 each launch)
// [31616,31744): packed conv1 bias f16x2 (64 uint2)
#define WS_GATE 192
#define WS_GNP  256
#define WS_W1F  25088
#define WS_W2F  29184
#define WS_FLAG 31232
#define WS_B1P  31616

typedef float    float4v __attribute__((ext_vector_type(4)));
typedef short    short8v __attribute__((ext_vector_type(8)));
typedef _Float16 half8v  __attribute__((ext_vector_type(8)));
typedef _Float16 half2v  __attribute__((ext_vector_type(2)));

union Q4 { uint4 q; short8v s; half8v h; };
union H2 { unsigned u; half2v h; };

__device__ __forceinline__ unsigned short bf16b(float f) {
    unsigned u = __builtin_bit_cast(unsigned, f);
    u = (u + 0x7FFFu + ((u >> 16) & 1u)) >> 16;   // RNE
    return (unsigned short)u;
}

__device__ __forceinline__ unsigned pkbf16(float a, float b) {
#if __has_builtin(__builtin_amdgcn_cvt_pk_bf16_f32)
    return __builtin_bit_cast(unsigned, __builtin_amdgcn_cvt_pk_bf16_f32(a, b));
#else
    return (unsigned)bf16b(a) | ((unsigned)bf16b(b) << 16);
#endif
}

__device__ __forceinline__ unsigned pkf16(float a, float b) {
#if __has_builtin(__builtin_amdgcn_cvt_pkrtz)
    return __builtin_bit_cast(unsigned, __builtin_amdgcn_cvt_pkrtz(a, b));
#else
    union { _Float16 h[2]; unsigned u; } p;
    p.h[0] = (_Float16)a; p.h[1] = (_Float16)b;
    return p.u;
#endif
}

__device__ __forceinline__ half2v pkmax0(half2v a) {
#if __has_builtin(__builtin_elementwise_max)
    return __builtin_elementwise_max(a, (half2v){(_Float16)0, (_Float16)0});
#else
    half2v r;
    r[0] = a[0] > (_Float16)0 ? a[0] : (_Float16)0;
    r[1] = a[1] > (_Float16)0 ? a[1] : (_Float16)0;
    return r;
#endif
}

// ---------------- kernel AUX: refsum | gatedots | prep+gating (one node) ----------------
__global__ void k_aux(const float* __restrict__ ref, const float* __restrict__ x,
                      const float* __restrict__ wg,  const float* __restrict__ wn,
                      const float* __restrict__ ew1, const float* __restrict__ ew2,
                      const float* __restrict__ eb1,
                      const float* __restrict__ noise,
                      const float* __restrict__ mw1, const float* __restrict__ mb1,
                      const float* __restrict__ mw2, const float* __restrict__ mb2,
                      const float* __restrict__ enw, const float* __restrict__ enb,
                      const float* __restrict__ fp,
                      float* __restrict__ ws, float* __restrict__ out) {
    __shared__ float sh[4][16][8];
    int blk = blockIdx.x, t = threadIdx.x;
    int* flags = (int*)(ws + WS_FLAG);

    if (blk < 192) {
        int bc = blk >> 2, chunk = blk & 3;
        const float4* p4 = (const float4*)(ref + (size_t)bc*65536 + (size_t)chunk*16384);
        float acc = 0.f;
        #pragma unroll
        for (int i = 0; i < 16; ++i) { float4 v = p4[i*256 + t]; acc += v.x + v.y + v.z + v.w; }
        #pragma unroll
        for (int m = 1; m <= 32; m <<= 1) acc += __shfl_xor(acc, m);
        if ((t & 63) == 0) sh[0][0][t >> 6] = acc;
        __syncthreads();
        if (t == 0) {
            ws[bc*4 + chunk] = sh[0][0][0] + sh[0][0][1] + sh[0][0][2] + sh[0][0][3];
            __hip_atomic_store(flags + blk, 1, __ATOMIC_RELEASE, __HIP_MEMORY_SCOPE_AGENT);
        }
        return;
    }
    if (blk < 384) {
        int r = blk - 192;
        int c = r >> 6, chunk = r & 63;
        int lane = t & 63, wv = t >> 6;
        int hw0 = chunk*1024 + t*4;
        const float4* wg4 = (const float4*)wg;
        const float4* wn4 = (const float4*)wn;
        const float4* x4  = (const float4*)x;
        float4 G[4], Nw[4];
        #pragma unroll
        for (int i = 0; i < 4; ++i) {
            G[i]  = wg4[c*65536 + hw0 + i];
            Nw[i] = wn4[c*65536 + hw0 + i];
        }
        for (int b = 0; b < 16; ++b) {
            float4 xv = x4[(b*3 + c)*16384 + chunk*256 + t];
            float xs[4] = {xv.x, xv.y, xv.z, xv.w};
            float aG[4] = {0,0,0,0}, aN[4] = {0,0,0,0};
            #pragma unroll
            for (int i = 0; i < 4; ++i) {
                aG[0] += xs[i]*G[i].x;  aG[1] += xs[i]*G[i].y;
                aG[2] += xs[i]*G[i].z;  aG[3] += xs[i]*G[i].w;
                aN[0] += xs[i]*Nw[i].x; aN[1] += xs[i]*Nw[i].y;
                aN[2] += xs[i]*Nw[i].z; aN[3] += xs[i]*Nw[i].w;
            }
            #pragma unroll
            for (int m = 1; m <= 32; m <<= 1) {
                #pragma unroll
                for (int e = 0; e < 4; ++e) {
                    aG[e] += __shfl_xor(aG[e], m);
                    aN[e] += __shfl_xor(aN[e], m);
                }
            }
            if (lane == 0) {
                #pragma unroll
                for (int e = 0; e < 4; ++e) { sh[wv][b][e] = aG[e]; sh[wv][b][4+e] = aN[e]; }
            }
        }
        __syncthreads();
        if (t < 128) {
            int b = t >> 3, s = t & 7;
            float v = sh[0][b][s] + sh[1][b][s] + sh[2][b][s] + sh[3][b][s];
            ws[WS_GNP + ((size_t)(c*64 + chunk)*16 + b)*8 + s] = v;
        }
        __syncthreads();
        if (t == 0)
            __hip_atomic_store(flags + blk, 1, __ATOMIC_RELEASE, __HIP_MEMORY_SCOPE_AGENT);
        return;
    }

    // ---- block 384: prep, then wait for all partials, then gating ----
    uint4* w1f = (uint4*)(ws + WS_W1F);
    for (int i = t; i < 1024; i += 256) {   // i = ((e*4+f)*4+qq)*16+mm
        int mm = i & 15, r = i >> 4, qq = r & 3, r2 = r >> 2, f = r2 & 3, e = r2 >> 2;
        const float* w1 = ew1 + e*1728 + (f*16 + mm)*27 + qq*8;
        int navail = 27 - qq*8;             // 8,8,8,3
        float v[8];
        #pragma unroll
        for (int j = 0; j < 8; ++j) v[j] = (j < navail) ? w1[j] : 0.f;
        uint4 q;
        q.x = pkbf16(v[0], v[1]); q.y = pkbf16(v[2], v[3]);
        q.z = pkbf16(v[4], v[5]); q.w = pkbf16(v[6], v[7]);
        w1f[i] = q;
    }
    uint4* w2f = (uint4*)(ws + WS_W2F);
    for (int i = t; i < 512; i += 256) {    // i = ((e*16+mm)*2+ks)*4+qq
        int qq = i & 3, r = i >> 2, ks = r & 1, r2 = r >> 1, mm = r2 & 15, e = r2 >> 4;
        uint4 q = make_uint4(0, 0, 0, 0);
        if (mm < 9) {                       // tap = mm, c = ks*32+qq*8+j
            float v[8];
            #pragma unroll
            for (int j = 0; j < 8; ++j) v[j] = ew2[e*576 + (ks*32 + qq*8 + j)*9 + mm];
            q.x = pkf16(v[0], v[1]); q.y = pkf16(v[2], v[3]);
            q.z = pkf16(v[4], v[5]); q.w = pkf16(v[6], v[7]);
        }
        w2f[i] = q;
    }
    // packed conv1 bias: [(e*4+f)*4+qq] -> f16x2 pairs for ch0..ch0+3
    uint2* b1p = (uint2*)(ws + WS_B1P);
    if (t < 64) {
        int qq = t & 3, r = t >> 2, f = r & 3, e = r >> 2;
        const float* bb = eb1 + e*64 + f*16 + qq*4;
        b1p[t] = make_uint2(pkf16(bb[0], bb[1]), pkf16(bb[2], bb[3]));
    }

    // wait for all 384 worker blocks (flags poison-reset to 0xAA each launch)
    if (t < 128) {
        #pragma unroll 1
        for (int u = 0; u < 3; ++u) {
            const int* f = flags + t*3 + u;
            while (__hip_atomic_load(f, __ATOMIC_ACQUIRE, __HIP_MEMORY_SCOPE_AGENT) != 1)
                __builtin_amdgcn_s_sleep(1);
        }
    }
    __syncthreads();

    // ---- gating ----
    __shared__ float GN2[48*8];
    __shared__ float gL[16][4], pL[16][4], cvs[2];
    if (t < 128) {
        #pragma unroll
        for (int u = 0; u < 3; ++u) {
            int idx = t*3 + u;               // < 384
            int bc = idx >> 3, s = idx & 7;
            int b = bc / 3, c = bc - b*3;
            float v = 0.f;
            for (int ch = 0; ch < 64; ++ch)
                v += ws[WS_GNP + ((size_t)(c*64 + ch)*16 + b)*8 + s];
            GN2[bc*8 + s] = v;
        }
    }
    __syncthreads();
    if (t < 16) {
        int b = t;
        float sc[3];
        for (int c = 0; c < 3; ++c) {
            int bc = b*3 + c;
            sc[c] = (ws[bc*4] + ws[bc*4+1] + ws[bc*4+2] + ws[bc*4+3]) * (1.f/256.f);
        }
        float pooled[12];
        for (int i = 0; i < 12; ++i) { int r = i % 6; pooled[i] = (r < 3) ? sc[r] : 0.f; }
        float m1[6];
        for (int o = 0; o < 6; ++o) {
            float a = mb1[o];
            for (int i = 0; i < 12; ++i) a += mw1[o*12 + i] * pooled[i];
            m1[o] = fmaxf(a, 0.f);
        }
        float m2[6];
        for (int o = 0; o < 6; ++o) {
            float a = mb2[o];
            for (int i = 0; i < 6; ++i) a += mw2[o*6 + i] * m1[i];
            m2[o] = a * fp[(size_t)o * 33024];   // * fre_prompt[o,0,0]
        }
        float dc[3];
        for (int o = 0; o < 3; ++o) {            // only real-part channels matter
            float a = enb[o];
            for (int i = 0; i < 6; ++i) a += enw[o*6 + i] * m2[i];
            dc[o] = fmaxf(a, 0.f) * (1.f/256.f); // mean of irfft2 = Re(DC)/256
        }
        float mx = fmaxf(dc[0], fmaxf(dc[1], dc[2]));
        float e0 = expf(dc[0]-mx), e1 = expf(dc[1]-mx), e2 = expf(dc[2]-mx);
        float inv = 1.f / (e0 + e1 + e2);
        float pc[3] = { e0*inv + 1.f, e1*inv + 1.f, e2*inv + 1.f };
        float cl[4], sg[4], nz[4];
        for (int e = 0; e < 4; ++e) {
            float a = 0.f, nr = 0.f;
            for (int c = 0; c < 3; ++c) {
                a  += pc[c] * GN2[(b*3 + c)*8 + e];
                nr += pc[c] * GN2[(b*3 + c)*8 + 4 + e];
            }
            cl[e] = a;
            float sp = (nr > 20.f) ? nr : log1pf(expf(nr));
            sg[e] = sp + 0.01f;
            nz[e] = a + noise[b*4 + e] * sg[e];
        }
        int i0 = 0; float v0 = nz[0];
        for (int e = 1; e < 4; ++e) if (nz[e] > v0) { v0 = nz[e]; i0 = e; }
        int i1 = -1; float v1 = -3.4e38f;
        for (int e = 0; e < 4; ++e) if (e != i0 && nz[e] > v1) { v1 = nz[e]; i1 = e; }
        float v2 = -3.4e38f;
        for (int e = 0; e < 4; ++e) if (e != i0 && e != i1 && nz[e] > v2) v2 = nz[e];
        float ex = expf(v1 - v0), den = 1.f + ex;
        float gate[4] = {0.f, 0.f, 0.f, 0.f};
        gate[i0] = 1.f/den; gate[i1] = ex/den;
        for (int e = 0; e < 4; ++e) {
            ws[WS_GATE + b*4 + e] = gate[e];
            gL[b][e] = gate[e];
            float thr = (nz[e] > v2) ? v2 : v1;   // thr_in = 3rd-largest, thr_out = 2nd
            pL[b][e] = 0.5f * (1.f + erff((cl[e] - thr) / sg[e] * 0.70710678118f));
        }
    }
    __syncthreads();
    if (t < 2) {
        float v[4];
        for (int e = 0; e < 4; ++e) {
            float s = 0.f;
            for (int b = 0; b < 16; ++b) s += (t == 0) ? gL[b][e] : pL[b][e];
            v[e] = s;
        }
        float mean = 0.25f * (v[0] + v[1] + v[2] + v[3]);
        float var = 0.f;
        for (int e = 0; e < 4; ++e) { float d = v[e] - mean; var += d*d; }
        var *= (1.f/3.f);
        cvs[t] = var / (mean*mean + 1e-10f);
    }
    __syncthreads();
    if (t == 0) out[1048576] = (cvs[0] + cvs[1]) * 0.01f;
}

// -------- kernel D: fused expert convs, packed-f16 epilogue, XCD-affinity swizzle --------
// One 16x16 output tile per block; 3 blocks/CU (LDS ~53.3 KB).
// blockIdx -> tile mapping groups every 8th block (same XCD under round-robin
// dispatch) onto a contiguous stripe of 512 tiles = 2 full images, so x-halos
// are re-read from the per-XCD L2 (2 x 786 KB < 4 MB) instead of HBM/L3.
__global__ __launch_bounds__(256, 3)
void k_experts(const float* __restrict__ x, const float* __restrict__ eb2,
               const float* __restrict__ ws, float* __restrict__ out) {
    __shared__ __align__(16) uint4 s_hid[324*8];     // 41472 B: hidden f16 [pix][64c] swizzled
    __shared__ __align__(16) char  s_mix[11808];     // in_s f32[1200] -> s_T f32[9*328]
    float* in_s = (float*)s_mix;
    float* s_T  = (float*)s_mix;

    int t = threadIdx.x;
    int bid = blockIdx.x;
    int logical = (bid & 7) * 512 + (bid >> 3);      // XCD-affinity stripe
    int b = logical >> 8, tile = logical & 255;
    int ty0 = (tile >> 4) * 16, tx0 = (tile & 15) * 16;
    const float* xb = x + (size_t)b * 196608;

    // ---- load input tile f32 [3][20][20] ----
    for (int i = t; i < 1200; i += 256) {
        int ci = i / 400, r = i - ci*400, iy = r / 20, ix = r - iy*20;
        int gy = ty0 - 2 + iy, gx = tx0 - 2 + ix;
        float v = 0.f;
        if ((unsigned)gy < 256u && (unsigned)gx < 256u) v = xb[ci*65536 + gy*256 + gx];
        in_s[i] = v;
    }
    __syncthreads();

    int lane = t & 63, wv = t >> 6;
    int qq = lane >> 4, mm = lane & 15;
    int oy = t >> 4, ox = t & 15;

    // per-lane k->tile-offset map (k = qq*8+j)
    int offj[8];
    #pragma unroll
    for (int j = 0; j < 8; ++j) {
        int k = qq*8 + j;
        if (k < 27) { int ci = k/9, r = k - ci*9, kh = r/3, kw = r - kh*3;
                      offj[j] = ci*400 + kh*20 + kw; }
        else offj[j] = -1;
    }

    // ---- build conv1 B-frags in registers: wave wv owns groups {wv, wv+4, ...} ----
    Q4 bfr[6];
    #pragma unroll
    for (int i = 0; i < 6; ++i) {
        int gidx = wv + i*4;
        if (gidx >= 21) break;
        int p = gidx*16 + mm;
        int py = p/18, px = p - py*18;
        int base = (p < 324) ? (py*20 + px) : 0;
        float v[8];
        #pragma unroll
        for (int j = 0; j < 8; ++j)
            v[j] = (offj[j] >= 0) ? in_s[base + offj[j]] : 0.f;
        bfr[i].q.x = pkbf16(v[0], v[1]); bfr[i].q.y = pkbf16(v[2], v[3]);
        bfr[i].q.z = pkbf16(v[4], v[5]); bfr[i].q.w = pkbf16(v[6], v[7]);
    }
    // in_s dead from here (s_T aliases s_mix; first T-write is >=2 barriers away)

    bool interior = (ty0 > 0) && (ty0 < 240) && (tx0 > 0) && (tx0 < 240);
    const float4 gates = *(const float4*)(ws + WS_GATE + b*4);
    float gv[4] = {gates.x, gates.y, gates.z, gates.w};
    const uint4* w1f = (const uint4*)(ws + WS_W1F);
    const uint4* w2f = (const uint4*)(ws + WS_W2F);
    const uint2* b1p = (const uint2*)(ws + WS_B1P);
    float accY = 0.f;

    for (int e = 0; e < 4; ++e) {
        float g = gv[e];
        if (g == 0.f) continue;                 // block-uniform

        // pre-packed conv2 B-frags (stage 1), loaded early to hide latency
        Q4 bw0, bw1;
        bw0.q = w2f[((e*16 + mm)*2 + 0)*4 + qq];
        bw1.q = w2f[((e*16 + mm)*2 + 1)*4 + qq];

        // pre-packed conv1 A-frags + packed f16 bias
        Q4 af[4];
        H2 bias01[4], bias23[4];
        #pragma unroll
        for (int f = 0; f < 4; ++f) {
            af[f].q = w1f[((e*4 + f)*4 + qq)*16 + mm];
            uint2 bp = b1p[(e*4 + f)*4 + qq];
            bias01[f].u = bp.x; bias23[f].u = bp.y;
        }

        // ---- phase B: hidden = relu(conv1+b1) -> s_hid (f16, swizzled)
        #pragma unroll
        for (int i = 0; i < 6; ++i) {
            int gidx = wv + i*4;
            if (gidx >= 21) break;
            int p = gidx*16 + mm;
            bool valid = p < 324;
            H2 mskv;
            if (!interior) {
                int py = p/18, px = p - py*18;
                int gy = ty0 - 1 + py, gx = tx0 - 1 + px;
                float msk = (((unsigned)gy < 256u) && ((unsigned)gx < 256u)) ? 1.f : 0.f;
                mskv.u = pkf16(msk, msk);
            }
            #pragma unroll
            for (int f = 0; f < 4; ++f) {
                float4v d = __builtin_amdgcn_mfma_f32_16x16x32_bf16(
                    af[f].s, bfr[i].s, (float4v){0.f,0.f,0.f,0.f}, 0, 0, 0);
                if (valid) {
                    H2 h01, h23;
                    h01.u = pkf16(d[0], d[1]);
                    h23.u = pkf16(d[2], d[3]);
                    h01.h = pkmax0(h01.h + bias01[f].h);
                    h23.h = pkmax0(h23.h + bias23[f].h);
                    if (!interior) { h01.h = h01.h * mskv.h; h23.h = h23.h * mskv.h; }
                    uint2 pk = make_uint2(h01.u, h23.u);
                    int ch0 = f*16 + qq*4;
                    int hchunk = ch0 >> 3, hsel = (ch0 >> 2) & 1;
                    ((uint2*)&s_hid[p*8 + ((hchunk + p) & 7)])[hsel] = pk;
                }
            }
        }
        __syncthreads();   // hid visible

        // ---- stage 1: T[pix][tap] = sum_c hid[pix][c] * w2[c][tap]
        for (int gi = wv; gi < 21; gi += 4) {
            int base = gi*16; if (base > 308) base = 308;   // tail overlap-recompute
            int p = base + mm;
            Q4 a0, a1;
            a0.q = s_hid[p*8 + ((qq + p) & 7)];
            a1.q = s_hid[p*8 + ((4 + qq + p) & 7)];
            float4v d = __builtin_amdgcn_mfma_f32_16x16x32_f16(
                a0.h, bw0.h, (float4v){0.f,0.f,0.f,0.f}, 0, 0, 0);
            d = __builtin_amdgcn_mfma_f32_16x16x32_f16(a1.h, bw1.h, d, 0, 0, 0);
            if (mm < 9) {   // col = tap = mm; rows = pixels base+qq*4+reg
                float4* dst = (float4*)&s_T[mm*328 + base + qq*4];
                *dst = make_float4(d[0], d[1], d[2], d[3]);
            }
        }
        __syncthreads();   // T visible

        // ---- stage 2: out = sum_tap T[(oy+kh)*18+ox+kw][tap]
        float oacc = 0.f;
        #pragma unroll
        for (int kh = 0; kh < 3; ++kh) {
            #pragma unroll
            for (int kw = 0; kw < 3; ++kw)
                oacc += s_T[(kh*3 + kw)*328 + (oy + kh)*18 + ox + kw];
        }
        accY += g * (oacc + eb2[e]);
    }
    out[(size_t)b*65536 + (ty0 + oy)*256 + tx0 + ox] = accY;
}

extern "C" void kernel_launch(void* const* d_in, const int* in_sizes, int n_in,
                              void* d_out, int out_size, void* d_ws, size_t ws_size,
                              hipStream_t stream) {
    (void)in_sizes; (void)n_in; (void)out_size; (void)ws_size;
    const float* x     = (const float*)d_in[0];
    const float* ref   = (const float*)d_in[1];
    const float* noise = (const float*)d_in[2];
    const float* mw1   = (const float*)d_in[3];
    const float* mb1   = (const float*)d_in[4];
    const float* mw2   = (const float*)d_in[5];
    const float* mb2   = (const float*)d_in[6];
    const float* enw   = (const float*)d_in[7];
    const float* enb   = (const float*)d_in[8];
    const float* fp    = (const float*)d_in[9];
    const float* wg    = (const float*)d_in[10];
    const float* wn    = (const float*)d_in[11];
    const float* ew1   = (const float*)d_in[12];
    const float* eb1   = (const float*)d_in[13];
    const float* ew2   = (const float*)d_in[14];
    const float* eb2   = (const float*)d_in[15];
    float* out = (float*)d_out;
    float* ws  = (float*)d_ws;

    k_aux    <<<385, 256, 0, stream>>>(ref, x, wg, wn, ew1, ew2, eb1,
                                       noise, mw1, mb1, mw2, mb2, enw, enb, fp,
                                       ws, out);
    k_experts<<<4096, 256, 0, stream>>>(x, eb2, ws, out);
}

// Round 14
// 184.717 us; speedup vs baseline: 1.0358x; 1.0358x over previous
//
#include <hip/hip_runtime.h>
#include <hip/hip_bf16.h>
#include <math.h>

// ---------------- workspace layout (float indices) ----------------
// [0,192)     : refsum partials  [bc=48][chunk=4]
// [192,256)   : gates[b*4+e]
// [256,24832) : gate-dot partials [c=3][chunk=64][b=16][8]  (G[4] then N[4])
// [25088,29184): packed conv1 A-frags  (1024 uint4)
// [29184,31232): packed conv2 B-frags  (512 uint4)
// [31616,31744): packed conv1 bias f16x2 (64 uint2)
#define WS_GATE 192
#define WS_GNP  256
#define WS_W1F  25088
#define WS_W2F  29184
#define WS_B1P  31616

typedef float    float4v __attribute__((ext_vector_type(4)));
typedef short    short8v __attribute__((ext_vector_type(8)));
typedef _Float16 half8v  __attribute__((ext_vector_type(8)));
typedef _Float16 half2v  __attribute__((ext_vector_type(2)));

union Q4 { uint4 q; short8v s; half8v h; };
union H2 { unsigned u; half2v h; };

__device__ __forceinline__ unsigned short bf16b(float f) {
    unsigned u = __builtin_bit_cast(unsigned, f);
    u = (u + 0x7FFFu + ((u >> 16) & 1u)) >> 16;   // RNE
    return (unsigned short)u;
}

__device__ __forceinline__ unsigned pkbf16(float a, float b) {
#if __has_builtin(__builtin_amdgcn_cvt_pk_bf16_f32)
    return __builtin_bit_cast(unsigned, __builtin_amdgcn_cvt_pk_bf16_f32(a, b));
#else
    return (unsigned)bf16b(a) | ((unsigned)bf16b(b) << 16);
#endif
}

__device__ __forceinline__ unsigned pkf16(float a, float b) {
#if __has_builtin(__builtin_amdgcn_cvt_pkrtz)
    return __builtin_bit_cast(unsigned, __builtin_amdgcn_cvt_pkrtz(a, b));
#else
    union { _Float16 h[2]; unsigned u; } p;
    p.h[0] = (_Float16)a; p.h[1] = (_Float16)b;
    return p.u;
#endif
}

__device__ __forceinline__ half2v pkmax0(half2v a) {
#if __has_builtin(__builtin_elementwise_max)
    return __builtin_elementwise_max(a, (half2v){(_Float16)0, (_Float16)0});
#else
    half2v r;
    r[0] = a[0] > (_Float16)0 ? a[0] : (_Float16)0;
    r[1] = a[1] > (_Float16)0 ? a[1] : (_Float16)0;
    return r;
#endif
}

// ---------------- kernel AUX: refsum (0..191) | gatedots (192..383) | prep (384) ----------------
__global__ void k_aux(const float* __restrict__ ref, const float* __restrict__ x,
                      const float* __restrict__ wg,  const float* __restrict__ wn,
                      const float* __restrict__ ew1, const float* __restrict__ ew2,
                      const float* __restrict__ eb1,
                      float* __restrict__ ws) {
    __shared__ float sh[4][16][8];
    int blk = blockIdx.x, t = threadIdx.x;

    if (blk < 192) {
        // ---- refsum partials: bc = blk>>2, chunk = blk&3 ----
        int bc = blk >> 2, chunk = blk & 3;
        const float4* p4 = (const float4*)(ref + (size_t)bc*65536 + (size_t)chunk*16384);
        float acc = 0.f;
        #pragma unroll
        for (int i = 0; i < 16; ++i) { float4 v = p4[i*256 + t]; acc += v.x + v.y + v.z + v.w; }
        #pragma unroll
        for (int m = 1; m <= 32; m <<= 1) acc += __shfl_xor(acc, m);
        if ((t & 63) == 0) sh[0][0][t >> 6] = acc;
        __syncthreads();
        if (t == 0) ws[bc*4 + chunk] = sh[0][0][0] + sh[0][0][1] + sh[0][0][2] + sh[0][0][3];
        return;
    }
    if (blk < 384) {
        // ---- gate-dot partials: wg/wn read exactly once ----
        int r = blk - 192;
        int c = r >> 6, chunk = r & 63;
        int lane = t & 63, wv = t >> 6;
        int hw0 = chunk*1024 + t*4;
        const float4* wg4 = (const float4*)wg;
        const float4* wn4 = (const float4*)wn;
        const float4* x4  = (const float4*)x;
        float4 G[4], Nw[4];
        #pragma unroll
        for (int i = 0; i < 4; ++i) {
            G[i]  = wg4[c*65536 + hw0 + i];
            Nw[i] = wn4[c*65536 + hw0 + i];
        }
        for (int b = 0; b < 16; ++b) {
            float4 xv = x4[(b*3 + c)*16384 + chunk*256 + t];
            float xs[4] = {xv.x, xv.y, xv.z, xv.w};
            float aG[4] = {0,0,0,0}, aN[4] = {0,0,0,0};
            #pragma unroll
            for (int i = 0; i < 4; ++i) {
                aG[0] += xs[i]*G[i].x;  aG[1] += xs[i]*G[i].y;
                aG[2] += xs[i]*G[i].z;  aG[3] += xs[i]*G[i].w;
                aN[0] += xs[i]*Nw[i].x; aN[1] += xs[i]*Nw[i].y;
                aN[2] += xs[i]*Nw[i].z; aN[3] += xs[i]*Nw[i].w;
            }
            #pragma unroll
            for (int m = 1; m <= 32; m <<= 1) {
                #pragma unroll
                for (int e = 0; e < 4; ++e) {
                    aG[e] += __shfl_xor(aG[e], m);
                    aN[e] += __shfl_xor(aN[e], m);
                }
            }
            if (lane == 0) {
                #pragma unroll
                for (int e = 0; e < 4; ++e) { sh[wv][b][e] = aG[e]; sh[wv][b][4+e] = aN[e]; }
            }
        }
        __syncthreads();
        if (t < 128) {
            int b = t >> 3, s = t & 7;
            float v = sh[0][b][s] + sh[1][b][s] + sh[2][b][s] + sh[3][b][s];
            ws[WS_GNP + ((size_t)(c*64 + chunk)*16 + b)*8 + s] = v;
        }
        return;
    }
    // ---- prep: pack conv weights + bias into MFMA-ready frags ----
    uint4* w1f = (uint4*)(ws + WS_W1F);
    for (int i = t; i < 1024; i += 256) {   // i = ((e*4+f)*4+qq)*16+mm
        int mm = i & 15, r = i >> 4, qq = r & 3, r2 = r >> 2, f = r2 & 3, e = r2 >> 2;
        const float* w1 = ew1 + e*1728 + (f*16 + mm)*27 + qq*8;
        int navail = 27 - qq*8;             // 8,8,8,3
        float v[8];
        #pragma unroll
        for (int j = 0; j < 8; ++j) v[j] = (j < navail) ? w1[j] : 0.f;
        uint4 q;
        q.x = pkbf16(v[0], v[1]); q.y = pkbf16(v[2], v[3]);
        q.z = pkbf16(v[4], v[5]); q.w = pkbf16(v[6], v[7]);
        w1f[i] = q;
    }
    uint4* w2f = (uint4*)(ws + WS_W2F);
    for (int i = t; i < 512; i += 256) {    // i = ((e*16+mm)*2+ks)*4+qq
        int qq = i & 3, r = i >> 2, ks = r & 1, r2 = r >> 1, mm = r2 & 15, e = r2 >> 4;
        uint4 q = make_uint4(0, 0, 0, 0);
        if (mm < 9) {                       // tap = mm, c = ks*32+qq*8+j
            float v[8];
            #pragma unroll
            for (int j = 0; j < 8; ++j) v[j] = ew2[e*576 + (ks*32 + qq*8 + j)*9 + mm];
            q.x = pkf16(v[0], v[1]); q.y = pkf16(v[2], v[3]);
            q.z = pkf16(v[4], v[5]); q.w = pkf16(v[6], v[7]);
        }
        w2f[i] = q;
    }
    // packed conv1 bias: [(e*4+f)*4+qq] -> f16x2 pairs for ch0..ch0+3
    uint2* b1p = (uint2*)(ws + WS_B1P);
    if (t < 64) {
        int qq = t & 3, r = t >> 2, f = r & 3, e = r >> 2;
        const float* bb = eb1 + e*64 + f*16 + qq*4;
        b1p[t] = make_uint2(pkf16(bb[0], bb[1]), pkf16(bb[2], bb[3]));
    }
}

// -------- kernel C: reduce partials + prompt + top-k + gates + loss --------
__global__ void k_gating(const float* __restrict__ noise,
                         const float* __restrict__ mw1, const float* __restrict__ mb1,
                         const float* __restrict__ mw2, const float* __restrict__ mb2,
                         const float* __restrict__ enw, const float* __restrict__ enb,
                         const float* __restrict__ fp,
                         float* __restrict__ ws, float* __restrict__ out) {
    __shared__ float GN2[48*8];          // [(b*3+c)][4G|4N]
    __shared__ float gL[16][4], pL[16][4], cvs[2];
    int t = threadIdx.x;                 // 128 threads
    #pragma unroll
    for (int u = 0; u < 3; ++u) {
        int idx = t*3 + u;               // < 384
        int bc = idx >> 3, s = idx & 7;
        int b = bc / 3, c = bc - b*3;
        float v = 0.f;
        for (int ch = 0; ch < 64; ++ch)
            v += ws[WS_GNP + ((size_t)(c*64 + ch)*16 + b)*8 + s];
        GN2[bc*8 + s] = v;
    }
    __syncthreads();
    if (t < 16) {
        int b = t;
        float sc[3];
        for (int c = 0; c < 3; ++c) {
            int bc = b*3 + c;
            sc[c] = (ws[bc*4] + ws[bc*4+1] + ws[bc*4+2] + ws[bc*4+3]) * (1.f/256.f);
        }
        float pooled[12];
        for (int i = 0; i < 12; ++i) { int r = i % 6; pooled[i] = (r < 3) ? sc[r] : 0.f; }
        float m1[6];
        for (int o = 0; o < 6; ++o) {
            float a = mb1[o];
            for (int i = 0; i < 12; ++i) a += mw1[o*12 + i] * pooled[i];
            m1[o] = fmaxf(a, 0.f);
        }
        float m2[6];
        for (int o = 0; o < 6; ++o) {
            float a = mb2[o];
            for (int i = 0; i < 6; ++i) a += mw2[o*6 + i] * m1[i];
            m2[o] = a * fp[(size_t)o * 33024];   // * fre_prompt[o,0,0]
        }
        float dc[3];
        for (int o = 0; o < 3; ++o) {            // only real-part channels matter
            float a = enb[o];
            for (int i = 0; i < 6; ++i) a += enw[o*6 + i] * m2[i];
            dc[o] = fmaxf(a, 0.f) * (1.f/256.f); // mean of irfft2 = Re(DC)/256
        }
        float mx = fmaxf(dc[0], fmaxf(dc[1], dc[2]));
        float e0 = expf(dc[0]-mx), e1 = expf(dc[1]-mx), e2 = expf(dc[2]-mx);
        float inv = 1.f / (e0 + e1 + e2);
        float pc[3] = { e0*inv + 1.f, e1*inv + 1.f, e2*inv + 1.f };
        float cl[4], sg[4], nz[4];
        for (int e = 0; e < 4; ++e) {
            float a = 0.f, nr = 0.f;
            for (int c = 0; c < 3; ++c) {
                a  += pc[c] * GN2[(b*3 + c)*8 + e];
                nr += pc[c] * GN2[(b*3 + c)*8 + 4 + e];
            }
            cl[e] = a;
            float sp = (nr > 20.f) ? nr : log1pf(expf(nr));
            sg[e] = sp + 0.01f;
            nz[e] = a + noise[b*4 + e] * sg[e];
        }
        int i0 = 0; float v0 = nz[0];
        for (int e = 1; e < 4; ++e) if (nz[e] > v0) { v0 = nz[e]; i0 = e; }
        int i1 = -1; float v1 = -3.4e38f;
        for (int e = 0; e < 4; ++e) if (e != i0 && nz[e] > v1) { v1 = nz[e]; i1 = e; }
        float v2 = -3.4e38f;
        for (int e = 0; e < 4; ++e) if (e != i0 && e != i1 && nz[e] > v2) v2 = nz[e];
        float ex = expf(v1 - v0), den = 1.f + ex;
        float gate[4] = {0.f, 0.f, 0.f, 0.f};
        gate[i0] = 1.f/den; gate[i1] = ex/den;
        for (int e = 0; e < 4; ++e) {
            ws[WS_GATE + b*4 + e] = gate[e];
            gL[b][e] = gate[e];
            float thr = (nz[e] > v2) ? v2 : v1;   // thr_in = 3rd-largest, thr_out = 2nd
            pL[b][e] = 0.5f * (1.f + erff((cl[e] - thr) / sg[e] * 0.70710678118f));
        }
    }
    __syncthreads();
    if (t < 2) {
        float v[4];
        for (int e = 0; e < 4; ++e) {
            float s = 0.f;
            for (int b = 0; b < 16; ++b) s += (t == 0) ? gL[b][e] : pL[b][e];
            v[e] = s;
        }
        float mean = 0.25f * (v[0] + v[1] + v[2] + v[3]);
        float var = 0.f;
        for (int e = 0; e < 4; ++e) { float d = v[e] - mean; var += d*d; }
        var *= (1.f/3.f);
        cvs[t] = var / (mean*mean + 1e-10f);
    }
    __syncthreads();
    if (t == 0) out[1048576] = (cvs[0] + cvs[1]) * 0.01f;
}

// -------- kernel D: fused expert convs, packed-f16 epilogue, XCD-affinity swizzle --------
// One 16x16 output tile per block; 3 blocks/CU (LDS ~53.3 KB).
__global__ __launch_bounds__(256, 3)
void k_experts(const float* __restrict__ x, const float* __restrict__ eb2,
               const float* __restrict__ ws, float* __restrict__ out) {
    __shared__ __align__(16) uint4 s_hid[324*8];     // 41472 B: hidden f16 [pix][64c] swizzled
    __shared__ __align__(16) char  s_mix[11808];     // in_s f32[1200] -> s_T f32[9*328]
    float* in_s = (float*)s_mix;
    float* s_T  = (float*)s_mix;

    int t = threadIdx.x;
    int bid = blockIdx.x;
    int logical = (bid & 7) * 512 + (bid >> 3);      // XCD-affinity stripe
    int b = logical >> 8, tile = logical & 255;
    int ty0 = (tile >> 4) * 16, tx0 = (tile & 15) * 16;
    const float* xb = x + (size_t)b * 196608;

    // ---- load input tile f32 [3][20][20] ----
    for (int i = t; i < 1200; i += 256) {
        int ci = i / 400, r = i - ci*400, iy = r / 20, ix = r - iy*20;
        int gy = ty0 - 2 + iy, gx = tx0 - 2 + ix;
        float v = 0.f;
        if ((unsigned)gy < 256u && (unsigned)gx < 256u) v = xb[ci*65536 + gy*256 + gx];
        in_s[i] = v;
    }
    __syncthreads();

    int lane = t & 63, wv = t >> 6;
    int qq = lane >> 4, mm = lane & 15;
    int oy = t >> 4, ox = t & 15;

    // per-lane k->tile-offset map (k = qq*8+j)
    int offj[8];
    #pragma unroll
    for (int j = 0; j < 8; ++j) {
        int k = qq*8 + j;
        if (k < 27) { int ci = k/9, r = k - ci*9, kh = r/3, kw = r - kh*3;
                      offj[j] = ci*400 + kh*20 + kw; }
        else offj[j] = -1;
    }

    // ---- build conv1 B-frags in registers: wave wv owns groups {wv, wv+4, ...} ----
    Q4 bfr[6];
    #pragma unroll
    for (int i = 0; i < 6; ++i) {
        int gidx = wv + i*4;
        if (gidx >= 21) break;
        int p = gidx*16 + mm;
        int py = p/18, px = p - py*18;
        int base = (p < 324) ? (py*20 + px) : 0;
        float v[8];
        #pragma unroll
        for (int j = 0; j < 8; ++j)
            v[j] = (offj[j] >= 0) ? in_s[base + offj[j]] : 0.f;
        bfr[i].q.x = pkbf16(v[0], v[1]); bfr[i].q.y = pkbf16(v[2], v[3]);
        bfr[i].q.z = pkbf16(v[4], v[5]); bfr[i].q.w = pkbf16(v[6], v[7]);
    }
    // in_s dead from here (s_T aliases s_mix; first T-write is >=2 barriers away)

    bool interior = (ty0 > 0) && (ty0 < 240) && (tx0 > 0) && (tx0 < 240);
    const float4 gates = *(const float4*)(ws + WS_GATE + b*4);
    float gv[4] = {gates.x, gates.y, gates.z, gates.w};
    const uint4* w1f = (const uint4*)(ws + WS_W1F);
    const uint4* w2f = (const uint4*)(ws + WS_W2F);
    const uint2* b1p = (const uint2*)(ws + WS_B1P);
    float accY = 0.f;

    for (int e = 0; e < 4; ++e) {
        float g = gv[e];
        if (g == 0.f) continue;                 // block-uniform

        // pre-packed conv2 B-frags (stage 1), loaded early to hide latency
        Q4 bw0, bw1;
        bw0.q = w2f[((e*16 + mm)*2 + 0)*4 + qq];
        bw1.q = w2f[((e*16 + mm)*2 + 1)*4 + qq];

        // pre-packed conv1 A-frags + packed f16 bias
        Q4 af[4];
        H2 bias01[4], bias23[4];
        #pragma unroll
        for (int f = 0; f < 4; ++f) {
            af[f].q = w1f[((e*4 + f)*4 + qq)*16 + mm];
            uint2 bp = b1p[(e*4 + f)*4 + qq];
            bias01[f].u = bp.x; bias23[f].u = bp.y;
        }

        // ---- phase B: hidden = relu(conv1+b1) -> s_hid (f16, swizzled)
        #pragma unroll
        for (int i = 0; i < 6; ++i) {
            int gidx = wv + i*4;
            if (gidx >= 21) break;
            int p = gidx*16 + mm;
            bool valid = p < 324;
            H2 mskv;
            if (!interior) {
                int py = p/18, px = p - py*18;
                int gy = ty0 - 1 + py, gx = tx0 - 1 + px;
                float msk = (((unsigned)gy < 256u) && ((unsigned)gx < 256u)) ? 1.f : 0.f;
                mskv.u = pkf16(msk, msk);
            }
            #pragma unroll
            for (int f = 0; f < 4; ++f) {
                float4v d = __builtin_amdgcn_mfma_f32_16x16x32_bf16(
                    af[f].s, bfr[i].s, (float4v){0.f,0.f,0.f,0.f}, 0, 0, 0);
                if (valid) {
                    H2 h01, h23;
                    h01.u = pkf16(d[0], d[1]);
                    h23.u = pkf16(d[2], d[3]);
                    h01.h = pkmax0(h01.h + bias01[f].h);
                    h23.h = pkmax0(h23.h + bias23[f].h);
                    if (!interior) { h01.h = h01.h * mskv.h; h23.h = h23.h * mskv.h; }
                    uint2 pk = make_uint2(h01.u, h23.u);
                    int ch0 = f*16 + qq*4;
                    int hchunk = ch0 >> 3, hsel = (ch0 >> 2) & 1;
                    ((uint2*)&s_hid[p*8 + ((hchunk + p) & 7)])[hsel] = pk;
                }
            }
        }
        __syncthreads();   // hid visible

        // ---- stage 1: T[pix][tap] = sum_c hid[pix][c] * w2[c][tap]
        for (int gi = wv; gi < 21; gi += 4) {
            int base = gi*16; if (base > 308) base = 308;   // tail overlap-recompute
            int p = base + mm;
            Q4 a0, a1;
            a0.q = s_hid[p*8 + ((qq + p) & 7)];
            a1.q = s_hid[p*8 + ((4 + qq + p) & 7)];
            float4v d = __builtin_amdgcn_mfma_f32_16x16x32_f16(
                a0.h, bw0.h, (float4v){0.f,0.f,0.f,0.f}, 0, 0, 0);
            d = __builtin_amdgcn_mfma_f32_16x16x32_f16(a1.h, bw1.h, d, 0, 0, 0);
            if (mm < 9) {   // col = tap = mm; rows = pixels base+qq*4+reg
                float4* dst = (float4*)&s_T[mm*328 + base + qq*4];
                *dst = make_float4(d[0], d[1], d[2], d[3]);
            }
        }
        __syncthreads();   // T visible

        // ---- stage 2: out = sum_tap T[(oy+kh)*18+ox+kw][tap]
        float oacc = 0.f;
        #pragma unroll
        for (int kh = 0; kh < 3; ++kh) {
            #pragma unroll
            for (int kw = 0; kw < 3; ++kw)
                oacc += s_T[(kh*3 + kw)*328 + (oy + kh)*18 + ox + kw];
        }
        accY += g * (oacc + eb2[e]);
    }
    out[(size_t)b*65536 + (ty0 + oy)*256 + tx0 + ox] = accY;
}

extern "C" void kernel_launch(void* const* d_in, const int* in_sizes, int n_in,
                              void* d_out, int out_size, void* d_ws, size_t ws_size,
                              hipStream_t stream) {
    (void)in_sizes; (void)n_in; (void)out_size; (void)ws_size;
    const float* x     = (const float*)d_in[0];
    const float* ref   = (const float*)d_in[1];
    const float* noise = (const float*)d_in[2];
    const float* mw1   = (const float*)d_in[3];
    const float* mb1   = (const float*)d_in[4];
    const float* mw2   = (const float*)d_in[5];
    const float* mb2   = (const float*)d_in[6];
    const float* enw   = (const float*)d_in[7];
    const float* enb   = (const float*)d_in[8];
    const float* fp    = (const float*)d_in[9];
    const float* wg    = (const float*)d_in[10];
    const float* wn    = (const float*)d_in[11];
    const float* ew1   = (const float*)d_in[12];
    const float* eb1   = (const float*)d_in[13];
    const float* ew2   = (const float*)d_in[14];
    const float* eb2   = (const float*)d_in[15];
    float* out = (float*)d_out;
    float* ws  = (float*)d_ws;

    k_aux    <<<385, 256, 0, stream>>>(ref, x, wg, wn, ew1, ew2, eb1, ws);
    k_gating <<<1, 128, 0, stream>>>(noise, mw1, mb1, mw2, mb2, enw, enb, fp, ws, out);
    k_experts<<<4096, 256, 0, stream>>>(x, eb2, ws, out);
}